// Round 5
// baseline (169.684 us; speedup 1.0000x reference)
//
#include <hip/hip_runtime.h>

#define BB 8
#define SS 2048
#define EE 512
#define HD 64
#define CHUNK 256
#define KT 64
#define NCH 8          // max chunks per 64-row q-block (combine layout)
#define TST 72         // K/V LDS row stride (elems)
#define PS32 36        // packed P^T LDS row stride (u32 units)
#define XRS 40         // qkv LDS row stride within kb chunk
#define XKB 1280       // qkv LDS kb-chunk stride (32 rows * XRS)
#define NITEMS 576     // 8 b * 72 (128-row q-blocks x ceil((Q+1)/2) chunks)

typedef __attribute__((ext_vector_type(8))) short bf16x8;
typedef __attribute__((ext_vector_type(4))) float f32x4;

static __device__ __forceinline__ unsigned short f2bf(float f) {
    unsigned u = __builtin_bit_cast(unsigned, f);
    u = (u + 0x7fffu + ((u >> 16) & 1u)) >> 16;  // RNE
    return (unsigned short)u;
}
static __device__ __forceinline__ float bf2f(unsigned short h) {
    unsigned u = ((unsigned)h) << 16;
    return __builtin_bit_cast(float, u);
}
// pack two f32 -> one u32 of 2x bf16 (trunc rounding, matches old P path)
static __device__ __forceinline__ unsigned pack2(float lo, float hi) {
    unsigned ulo = __builtin_bit_cast(unsigned, lo) >> 16;
    unsigned uhi = __builtin_bit_cast(unsigned, hi) & 0xffff0000u;
    return uhi | ulo;
}

// pack W (fp32 [E][64] x3) -> bf16 fragment layout; Wq pre-scaled by HEAD^-0.5.
// Also zeroes the split-K finisher counters (stream-ordered before attn).
__global__ __launch_bounds__(256) void pack_w_kernel(
    const float* __restrict__ Wq, const float* __restrict__ Wk, const float* __restrict__ Wv,
    unsigned short* __restrict__ Wt, int* __restrict__ cnt) {
    if (blockIdx.x == 0 && threadIdx.x < BB * 16) cnt[threadIdx.x] = 0;
    int tid = blockIdx.x * 256 + threadIdx.x;
    if (tid >= 3 * EE * HD) return;
    int w_idx = tid / (EE * HD);
    int rem = tid % (EE * HD);
    int kk = rem / HD, n = rem % HD;
    const float* Wsrc = (w_idx == 0) ? Wq : ((w_idx == 1) ? Wk : Wv);
    float val = Wsrc[kk * HD + n];
    if (w_idx == 0) val *= 0.125f;  // fold scores scale into q
    int kb = kk >> 5, kr = kk & 31, quad = kr >> 3, j = kr & 7;
    int t = n >> 4, c = n & 15;
    int lane = quad * 16 + c;
    Wt[w_idx * (EE * HD) + ((kb * 4 + t) * 64 + lane) * 8 + j] = f2bf(val);
}

// QKV v6: dual orientation. q,k computed swapped (d on reg axis -> ushort4
// stores along d); V computed in the ORIGINAL orientation (s on reg axis ->
// ushort4 stores along s of vT[d][s]). Same fragments for both.
__global__ __launch_bounds__(256) void qkv_kernel(
    const float* __restrict__ x,            // [B*S, E] fp32
    const unsigned short* __restrict__ Wt,  // packed bf16, 3*E*64
    unsigned short* __restrict__ q,
    unsigned short* __restrict__ k,
    unsigned short* __restrict__ vT) {
    __shared__ __align__(16) unsigned short Xs[16 * XKB];  // 40 KB
    const int tid = threadIdx.x;
    const int lane = tid & 63;
    const int t = tid >> 6;  // wave = output col-tile 0..3
    const int c = lane & 15, quad = lane >> 4;
    const int r0 = blockIdx.x * 32;

    // stage 32 rows x 512 cols fp32 -> bf16 LDS, kb-major
    const float* xt = x + (size_t)r0 * EE;
#pragma unroll
    for (int i = 0; i < 16; ++i) {
        int fi = i * 256 + tid;  // float4 index 0..4095
        int e4 = fi * 4;
        float4 v4 = *(const float4*)(xt + e4);
        int row = e4 >> 9, col = e4 & 511;
        int kb = col >> 5, cc = col & 31;
        ushort4 pk;
        pk.x = f2bf(v4.x); pk.y = f2bf(v4.y); pk.z = f2bf(v4.z); pk.w = f2bf(v4.w);
        *(ushort4*)(&Xs[kb * XKB + row * XRS + cc]) = pk;
    }
    __syncthreads();

    f32x4 acc[2][3];
#pragma unroll
    for (int rt = 0; rt < 2; ++rt)
        for (int m = 0; m < 3; ++m) acc[rt][m] = (f32x4){0.f, 0.f, 0.f, 0.f};

    const unsigned short* wbase0 = Wt + t * 512 + lane * 8;
#pragma unroll
    for (int kb = 0; kb < EE / 32; ++kb) {
        const unsigned short* wb = wbase0 + kb * 2048;
        bf16x8 wfrag[3];
#pragma unroll
        for (int m = 0; m < 3; ++m) wfrag[m] = *(const bf16x8*)(wb + m * (EE * HD));
#pragma unroll
        for (int rt = 0; rt < 2; ++rt) {
            bf16x8 xfrag = *(const bf16x8*)(&Xs[kb * XKB + (rt * 16 + c) * XRS + quad * 8]);
            // q,k swapped: D[Wcol][xrow]
            acc[rt][0] = __builtin_amdgcn_mfma_f32_16x16x32_bf16(wfrag[0], xfrag, acc[rt][0], 0, 0, 0);
            acc[rt][1] = __builtin_amdgcn_mfma_f32_16x16x32_bf16(wfrag[1], xfrag, acc[rt][1], 0, 0, 0);
            // v original: D[xrow][Wcol]
            acc[rt][2] = __builtin_amdgcn_mfma_f32_16x16x32_bf16(xfrag, wfrag[2], acc[rt][2], 0, 0, 0);
        }
    }

    const int colq = t * 16 + quad * 4;   // q,k: 4 consecutive d
    const int colv = t * 16 + c;          // v: fixed d per lane
#pragma unroll
    for (int rt = 0; rt < 2; ++rt) {
        const int row = r0 + rt * 16 + c;
        ushort4 pq, pkk;
        pq.x = f2bf(acc[rt][0][0]); pq.y = f2bf(acc[rt][0][1]);
        pq.z = f2bf(acc[rt][0][2]); pq.w = f2bf(acc[rt][0][3]);
        pkk.x = f2bf(acc[rt][1][0]); pkk.y = f2bf(acc[rt][1][1]);
        pkk.z = f2bf(acc[rt][1][2]); pkk.w = f2bf(acc[rt][1][3]);
        *(ushort4*)(q + (size_t)row * HD + colq) = pq;
        *(ushort4*)(k + (size_t)row * HD + colq) = pkk;
        // v: rows (s) on reg axis -> 4 consecutive s at fixed d
        const int vrow = r0 + rt * 16 + quad * 4;
        int b_ = vrow >> 11, sb = vrow & (SS - 1);
        ushort4 pv;
        pv.x = f2bf(acc[rt][2][0]); pv.y = f2bf(acc[rt][2][1]);
        pv.z = f2bf(acc[rt][2][2]); pv.w = f2bf(acc[rt][2][3]);
        *(ushort4*)(vT + ((size_t)b_ * HD + colv) * SS + sb) = pv;
    }
}

// Split-K attention, R5: combine kernel FUSED as a last-finisher tail.
// Multi-chunk items write po/pl, publish via __threadfence + device-scope
// atomicAdd on a per-(b,Q) counter; the last finisher fences (acquire) and
// combines all 128 rows in-place. Big-first ordering hides the tail.
__global__ __launch_bounds__(256, 3) void attn_kernel(
    const unsigned short* __restrict__ q,
    const unsigned short* __restrict__ k,
    const unsigned short* __restrict__ vT,
    const int* __restrict__ mask,
    unsigned short* __restrict__ po,   // [B][32 qb][NCH][64 rows][64 d] bf16
    float* __restrict__ pl,            // [B][32 qb][NCH][64 rows] fp32
    int* __restrict__ cnt,             // [B*16] finisher counters (zeroed)
    float* __restrict__ out) {
    __shared__ __align__(16) unsigned short Ks[2][64 * TST];
    __shared__ __align__(16) unsigned short Vs[2][64 * TST];
    __shared__ __align__(16) unsigned int Ps32[4][16 * PS32];  // 9216 B
    __shared__ int last_flag;
    const int tid = threadIdx.x;
    const int lane = tid & 63, wave = tid >> 6;
    const int c = lane & 15, quad = lane >> 4;

    int t = NITEMS - 1 - blockIdx.x;       // big items first (low blockIdx)
    const int b_ = t / 72;
    int r = t % 72;
    int g = 0;
    while ((g + 1) * (g + 2) <= r) ++g;    // group: Q in {2g,2g+1}, nch=g+1
    int rr = r - g * (g + 1);
    const int Q = 2 * g + rr / (g + 1);
    const int cx = rr % (g + 1);
    const int kstart = cx * CHUNK;
    const int kend = min(kstart + CHUNK, Q * 128 + 128);
    const int ntiles = (kend - kstart) >> 6;   // 1..4 whole tiles
    const int nch_active = Q / 2 + 1;
    const int r0 = Q * 128 + wave * 32;        // this wave's first row

    const unsigned short* qb_p = q + (size_t)b_ * SS * HD;
    const unsigned short* kb_p = k + (size_t)b_ * SS * HD;
    const unsigned short* vb = vT + (size_t)b_ * HD * SS;
    const int* mb = mask + b_ * SS;

    // dead-tile clamp: prefix mask => tiles whose first key is masked are all-zero
    int ntl = 0;
#pragma unroll
    for (int i = 0; i < 4; ++i)
        if (i < ntiles && mb[kstart + i * KT] != 0) ntl = i + 1;

    bf16x8 aq[2][2];
#pragma unroll
    for (int rt = 0; rt < 2; ++rt) {
        const unsigned short* qrow = qb_p + (size_t)(r0 + rt * 16 + c) * HD + quad * 8;
        aq[rt][0] = *(const bf16x8*)(qrow);
        aq[rt][1] = *(const bf16x8*)(qrow + 32);
    }

    f32x4 o[2][4];   // o[rt][tt]: O^T block, row d=16tt+4quad+reg, col qrow=c
    float l_part[2] = {0.f, 0.f};
#pragma unroll
    for (int rt = 0; rt < 2; ++rt)
        for (int tt = 0; tt < 4; ++tt) o[rt][tt] = (f32x4){0.f, 0.f, 0.f, 0.f};

    // T14 split staging: global->reg (issue early), reg->LDS (write late).
    bf16x8 sk[2], sv[2];
    auto stage_load = [&](int k0) {
        const unsigned short* ksrc = kb_p + (size_t)k0 * HD;
#pragma unroll
        for (int rnd = 0; rnd < 2; ++rnd) {
            int e = (rnd * 256 + tid) * 8;
            sk[rnd] = *(const bf16x8*)(ksrc + e);
            int t8 = rnd * 256 + tid;
            int vr = t8 >> 3, vc = (t8 & 7) * 8;
            sv[rnd] = *(const bf16x8*)(vb + (size_t)vr * SS + k0 + vc);
        }
    };
    auto stage_write = [&](int buf) {
        unsigned short* kd = &Ks[buf][0];
        unsigned short* vd = &Vs[buf][0];
#pragma unroll
        for (int rnd = 0; rnd < 2; ++rnd) {
            int e = (rnd * 256 + tid) * 8;
            int krow = e >> 6, kcol = e & 63;
            *(bf16x8*)(kd + krow * TST + kcol) = sk[rnd];
            int t8 = rnd * 256 + tid;
            int vr = t8 >> 3, vc = (t8 & 7) * 8;
            *(bf16x8*)(vd + vr * TST + vc) = sv[rnd];
        }
    };

    if (ntl > 0) {
        stage_load(kstart);
        stage_write(0);
        for (int kt = 0; kt < ntl; ++kt) {
            __syncthreads();
            const int k0 = kstart + kt * KT;
            const bool pre = (kt + 1 < ntl);
            if (pre) stage_load(k0 + KT);        // issue next tile's globals NOW
            const unsigned short* ks = &Ks[kt & 1][0];
            const unsigned short* vs = &Vs[kt & 1][0];
            const bool vall = (mb[k0 + KT - 1] != 0);  // whole tile unmasked

            bf16x8 kf[4][2];
#pragma unroll
            for (int kg = 0; kg < 4; ++kg) {
                kf[kg][0] = *(const bf16x8*)(ks + (kg * 16 + c) * TST + quad * 8);
                kf[kg][1] = *(const bf16x8*)(ks + (kg * 16 + c) * TST + 32 + quad * 8);
            }

            bf16x8 pB[2][2];
#pragma unroll
            for (int rt = 0; rt < 2; ++rt) {
                const int rbase = r0 + rt * 16;
                const int qr = rbase + c;                 // this lane's q-row
                const bool fullc = (k0 + KT <= rbase);
                f32x4 accs4[4];
                __builtin_amdgcn_s_setprio(1);
#pragma unroll
                for (int kg = 0; kg < 4; ++kg) {          // swapped: P^T[key][qrow]
                    f32x4 a = (f32x4){0.f, 0.f, 0.f, 0.f};
                    a = __builtin_amdgcn_mfma_f32_16x16x32_bf16(kf[kg][0], aq[rt][0], a, 0, 0, 0);
                    a = __builtin_amdgcn_mfma_f32_16x16x32_bf16(kf[kg][1], aq[rt][1], a, 0, 0, 0);
                    accs4[kg] = a;
                }
                __builtin_amdgcn_s_setprio(0);
                unsigned int* pb = &Ps32[wave][0];
                if (fullc && vall) {
                    // easy path: no masking at all
#pragma unroll
                    for (int kg = 0; kg < 4; ++kg) {
                        float pe[4];
#pragma unroll
                        for (int rr2 = 0; rr2 < 4; ++rr2) {
                            float p = __expf(fminf(accs4[kg][rr2], 80.f));
                            l_part[rt] += p;
                            pe[rr2] = p;
                        }
                        uint2 w2;
                        w2.x = pack2(pe[0], pe[1]);
                        w2.y = pack2(pe[2], pe[3]);
                        *(uint2*)(pb + c * PS32 + kg * 8 + quad * 2) = w2;
                    }
                } else {
                    // hard path: padding and/or causal boundary
                    int mks[4][4];
#pragma unroll
                    for (int kg = 0; kg < 4; ++kg) {
                        int4 mv = *(const int4*)(mb + k0 + kg * 16 + quad * 4);
                        mks[kg][0] = mv.x; mks[kg][1] = mv.y; mks[kg][2] = mv.z; mks[kg][3] = mv.w;
                    }
#pragma unroll
                    for (int kg = 0; kg < 4; ++kg) {
                        float pe[4];
#pragma unroll
                        for (int rr2 = 0; rr2 < 4; ++rr2) {
                            int key = k0 + kg * 16 + quad * 4 + rr2;
                            bool keep = (mks[kg][rr2] != 0) && (fullc || key <= qr);
                            float e = __expf(fminf(accs4[kg][rr2], 80.f));
                            float p = keep ? e : 0.f;
                            l_part[rt] += p;
                            pe[rr2] = p;
                        }
                        uint2 w2;
                        w2.x = pack2(pe[0], pe[1]);
                        w2.y = pack2(pe[2], pe[3]);
                        *(uint2*)(pb + c * PS32 + kg * 8 + quad * 2) = w2;
                    }
                }
                const unsigned short* pb16 = (const unsigned short*)pb;
                pB[rt][0] = *(const bf16x8*)(pb16 + c * (PS32 * 2) + quad * 8);
                pB[rt][1] = *(const bf16x8*)(pb16 + c * (PS32 * 2) + 32 + quad * 8);
            }

            // PV: O^T += V^T * P^T ; V fragments read once, used for both rt
#pragma unroll
            for (int tt = 0; tt < 4; ++tt) {
                bf16x8 bv0 = *(const bf16x8*)(vs + (tt * 16 + c) * TST + quad * 8);
                bf16x8 bv1 = *(const bf16x8*)(vs + (tt * 16 + c) * TST + 32 + quad * 8);
                __builtin_amdgcn_s_setprio(1);
#pragma unroll
                for (int rt = 0; rt < 2; ++rt) {
                    o[rt][tt] = __builtin_amdgcn_mfma_f32_16x16x32_bf16(bv0, pB[rt][0], o[rt][tt], 0, 0, 0);
                    o[rt][tt] = __builtin_amdgcn_mfma_f32_16x16x32_bf16(bv1, pB[rt][1], o[rt][tt], 0, 0, 0);
                }
                __builtin_amdgcn_s_setprio(0);
            }

            if (pre) stage_write((kt + 1) & 1);  // latency hidden under compute
        }
    }

    // l reduce: sum partials across the 4 quads (same qcol c)
    float lv[2];
#pragma unroll
    for (int rt = 0; rt < 2; ++rt) {
        float s = l_part[rt];
        s += __shfl_xor(s, 16);
        s += __shfl_xor(s, 32);
        lv[rt] = s;
    }

    if (nch_active == 1) {
        // rows < 256: sole chunk, final output directly (vector stores)
#pragma unroll
        for (int rt = 0; rt < 2; ++rt) {
            int row = r0 + rt * 16 + c;
            float l = lv[rt];
            float inv = (l > 0.f) ? 1.f / l : 0.f;
#pragma unroll
            for (int tt = 0; tt < 4; ++tt) {
                float4 o4;
                o4.x = o[rt][tt][0] * inv; o4.y = o[rt][tt][1] * inv;
                o4.z = o[rt][tt][2] * inv; o4.w = o[rt][tt][3] * inv;
                *(float4*)(out + ((size_t)b_ * SS + row) * HD + tt * 16 + quad * 4) = o4;
            }
        }
        return;
    }

    // multi-chunk: write partials
#pragma unroll
    for (int rt = 0; rt < 2; ++rt) {
        int row_abs = r0 + rt * 16 + c;
        int qb_i = row_abs >> 6, rl = row_abs & 63;
        size_t base = (size_t)(b_ * 32 + qb_i) * NCH + cx;
        float l = lv[rt];
        float inv = (l > 0.f) ? 1.f / l : 0.f;
#pragma unroll
        for (int tt = 0; tt < 4; ++tt) {
            ushort4 pk;
            pk.x = f2bf(o[rt][tt][0] * inv); pk.y = f2bf(o[rt][tt][1] * inv);
            pk.z = f2bf(o[rt][tt][2] * inv); pk.w = f2bf(o[rt][tt][3] * inv);
            *(ushort4*)(po + base * 4096 + (size_t)rl * 64 + tt * 16 + quad * 4) = pk;
        }
        if (quad == 0) pl[base * 64 + rl] = l;
    }

    // publish: barrier drains vmcnt (stores in L2); tid0 fences (XCD L2
    // writeback) then bumps the device-scope counter.
    __syncthreads();
    if (tid == 0) {
        __threadfence();
        int prev = atomicAdd(&cnt[b_ * 16 + Q], 1);
        last_flag = (prev == nch_active - 1) ? 1 : 0;
    }
    __syncthreads();
    if (!last_flag) return;
    __threadfence();  // acquire: invalidate local caches before reading peers' po/pl

    // finisher: combine all 128 rows x 64 d of this (b_, Q) group
#pragma unroll
    for (int it = 0; it < 8; ++it) {
        int gidx = it * 256 + tid;          // 0..2047
        int rl128 = gidx >> 4, d4 = (gidx & 15) * 4;
        int row = Q * 128 + rl128;
        int qb = row >> 6, rl = row & 63;
        size_t base = (size_t)(b_ * 32 + qb) * NCH;
        float L = 0.f;
        float a0 = 0.f, a1 = 0.f, a2 = 0.f, a3 = 0.f;
        for (int cc = 0; cc < nch_active; ++cc) {
            float l = pl[(base + cc) * 64 + rl];
            L += l;
            ushort4 pk = *(const ushort4*)(po + (base + cc) * 4096 + (size_t)rl * 64 + d4);
            a0 += l * bf2f(pk.x);
            a1 += l * bf2f(pk.y);
            a2 += l * bf2f(pk.z);
            a3 += l * bf2f(pk.w);
        }
        float inv = (L > 0.f) ? 1.f / L : 0.f;
        float4 o4;
        o4.x = a0 * inv; o4.y = a1 * inv; o4.z = a2 * inv; o4.w = a3 * inv;
        *(float4*)(out + ((size_t)b_ * SS + row) * HD + d4) = o4;
    }
}

extern "C" void kernel_launch(void* const* d_in, const int* in_sizes, int n_in,
                              void* d_out, int out_size, void* d_ws, size_t ws_size,
                              hipStream_t stream) {
    const float* x = (const float*)d_in[0];
    const float* Wq = (const float*)d_in[1];
    const float* Wk = (const float*)d_in[2];
    const float* Wv = (const float*)d_in[3];
    const int* mask = (const int*)d_in[4];
    float* out = (float*)d_out;

    // ws: Wt[98304] | q,k,vT[3x1048576] bf16 | po bf16 | pl fp32 | cnt int
    unsigned short* ws = (unsigned short*)d_ws;
    unsigned short* Wt = ws;
    unsigned short* q = Wt + 3 * EE * HD;
    unsigned short* kk = q + (size_t)BB * SS * HD;
    unsigned short* vT = kk + (size_t)BB * SS * HD;
    unsigned short* po = vT + (size_t)BB * SS * HD;
    float* pl = (float*)(po + (size_t)BB * 32 * NCH * 4096);
    int* cnt = (int*)(pl + (size_t)BB * 32 * NCH * 64);

    pack_w_kernel<<<dim3((3 * EE * HD + 255) / 256), dim3(256), 0, stream>>>(Wq, Wk, Wv, Wt, cnt);
    qkv_kernel<<<dim3(BB * SS / 32), dim3(256), 0, stream>>>(x, Wt, q, kk, vT);
    attn_kernel<<<dim3(NITEMS), dim3(256), 0, stream>>>(q, kk, vT, mask, po, pl, cnt, out);
}

// Round 6
// 108.718 us; speedup vs baseline: 1.5608x; 1.5608x over previous
//
#include <hip/hip_runtime.h>

#define BB 8
#define SS 2048
#define EE 512
#define HD 64
#define CHUNK 256
#define KT 64
#define NCH 8          // max chunks per 64-row q-block (combine layout)
#define PST 72         // P LDS row stride (elems)
#define TST 72         // K/V LDS row stride (elems)
#define XRS 40         // qkv LDS row stride within kb chunk
#define XKB 1280       // qkv LDS kb-chunk stride (32 rows * XRS)
#define NITEMS 576     // 8 b * 72 (128-row q-blocks x ceil((Q+1)/2) chunks)

typedef __attribute__((ext_vector_type(8))) short bf16x8;
typedef __attribute__((ext_vector_type(4))) float f32x4;

static __device__ __forceinline__ unsigned short f2bf(float f) {
    unsigned u = __builtin_bit_cast(unsigned, f);
    u = (u + 0x7fffu + ((u >> 16) & 1u)) >> 16;  // RNE
    return (unsigned short)u;
}
static __device__ __forceinline__ unsigned short f2bf_trunc(float f) {
    return (unsigned short)(__builtin_bit_cast(unsigned, f) >> 16);
}
static __device__ __forceinline__ float bf2f(unsigned short h) {
    unsigned u = ((unsigned)h) << 16;
    return __builtin_bit_cast(float, u);
}

// pack W (fp32 [E][64] x3) -> bf16 B-fragment layout; Wq pre-scaled by HEAD^-0.5.
__global__ __launch_bounds__(256) void pack_w_kernel(
    const float* __restrict__ Wq, const float* __restrict__ Wk, const float* __restrict__ Wv,
    unsigned short* __restrict__ Wt) {
    int tid = blockIdx.x * 256 + threadIdx.x;
    if (tid >= 3 * EE * HD) return;
    int w_idx = tid / (EE * HD);
    int rem = tid % (EE * HD);
    int kk = rem / HD, n = rem % HD;
    const float* Wsrc = (w_idx == 0) ? Wq : ((w_idx == 1) ? Wk : Wv);
    float val = Wsrc[kk * HD + n];
    if (w_idx == 0) val *= 0.125f;  // fold scores scale into q
    int kb = kk >> 5, kr = kk & 31, quad = kr >> 3, j = kr & 7;
    int t = n >> 4, c = n & 15;
    int lane = quad * 16 + c;
    Wt[w_idx * (EE * HD) + ((kb * 4 + t) * 64 + lane) * 8 + j] = f2bf(val);
}

// QKV v3: 512 blocks x 256 thr, 32 rows/block. x staged kb-major in LDS (40 KB).
__global__ __launch_bounds__(256) void qkv_kernel(
    const float* __restrict__ x,            // [B*S, E] fp32
    const unsigned short* __restrict__ Wt,  // packed bf16, 3*E*64
    unsigned short* __restrict__ q,
    unsigned short* __restrict__ k,
    unsigned short* __restrict__ vT) {
    __shared__ __align__(16) unsigned short Xs[16 * XKB];  // 40 KB
    const int tid = threadIdx.x;
    const int lane = tid & 63;
    const int t = tid >> 6;  // wave = output col-tile 0..3
    const int c = lane & 15, quad = lane >> 4;
    const int r0 = blockIdx.x * 32;

    // stage 32 rows x 512 cols fp32 -> bf16 LDS, kb-major
    const float* xt = x + (size_t)r0 * EE;
#pragma unroll
    for (int i = 0; i < 16; ++i) {
        int fi = i * 256 + tid;  // float4 index 0..4095
        int e4 = fi * 4;
        float4 v4 = *(const float4*)(xt + e4);
        int row = e4 >> 9, col = e4 & 511;
        int kb = col >> 5, cc = col & 31;
        ushort4 pk;
        pk.x = f2bf(v4.x); pk.y = f2bf(v4.y); pk.z = f2bf(v4.z); pk.w = f2bf(v4.w);
        *(ushort4*)(&Xs[kb * XKB + row * XRS + cc]) = pk;
    }
    __syncthreads();

    f32x4 acc[2][3];
#pragma unroll
    for (int rt = 0; rt < 2; ++rt)
        for (int m = 0; m < 3; ++m) acc[rt][m] = (f32x4){0.f, 0.f, 0.f, 0.f};

    const unsigned short* wbase0 = Wt + t * 512 + lane * 8;
#pragma unroll
    for (int kb = 0; kb < EE / 32; ++kb) {
        const unsigned short* wb = wbase0 + kb * 2048;
        bf16x8 bfrag[3];
#pragma unroll
        for (int m = 0; m < 3; ++m) bfrag[m] = *(const bf16x8*)(wb + m * (EE * HD));
#pragma unroll
        for (int rt = 0; rt < 2; ++rt) {
            bf16x8 afrag = *(const bf16x8*)(&Xs[kb * XKB + (rt * 16 + c) * XRS + quad * 8]);
#pragma unroll
            for (int m = 0; m < 3; ++m)
                acc[rt][m] = __builtin_amdgcn_mfma_f32_16x16x32_bf16(afrag, bfrag[m], acc[rt][m], 0, 0, 0);
        }
    }

    const int col = t * 16 + c;
#pragma unroll
    for (int rt = 0; rt < 2; ++rt) {
        const int rb = r0 + rt * 16;
        for (int r = 0; r < 4; ++r) {
            int row = rb + quad * 4 + r;
            q[(size_t)row * HD + col] = f2bf(acc[rt][0][r]);
            k[(size_t)row * HD + col] = f2bf(acc[rt][1][r]);
        }
        int row = rb + quad * 4;
        int b_ = row >> 11, sb = row & (SS - 1);
        ushort4 pk;
        pk.x = f2bf(acc[rt][2][0]); pk.y = f2bf(acc[rt][2][1]);
        pk.z = f2bf(acc[rt][2][2]); pk.w = f2bf(acc[rt][2][3]);
        *(ushort4*)(vT + ((size_t)b_ * HD + col) * SS + sb) = pk;
    }
}

// Split-K attention, 128-row q-items, direct blockIdx mapping.
// R12: T14 async-stage split (global->reg early, LDS write after compute),
// pa[2][2] hoist so V fragments are read once per tile (not per rt),
// mask loads hoisted per-tile, setprio around MFMA clusters.
__global__ __launch_bounds__(256, 3) void attn_kernel(
    const unsigned short* __restrict__ q,
    const unsigned short* __restrict__ k,
    const unsigned short* __restrict__ vT,
    const int* __restrict__ mask,
    unsigned short* __restrict__ po,   // [B][32 qb][NCH][64 rows][64 d] bf16
    float* __restrict__ pl,            // [B][32 qb][NCH][64 rows] fp32
    float* __restrict__ out) {
    __shared__ __align__(16) unsigned short Ks[2][64 * TST];
    __shared__ __align__(16) unsigned short Vs[2][64 * TST];
    __shared__ __align__(16) unsigned short Ps[4][16 * PST];
    const int tid = threadIdx.x;
    const int lane = tid & 63, wave = tid >> 6;
    const int c = lane & 15, quad = lane >> 4;

    int t = NITEMS - 1 - blockIdx.x;       // big items first (low blockIdx)
    const int b_ = t / 72;
    int r = t % 72;
    int g = 0;
    while ((g + 1) * (g + 2) <= r) ++g;    // group: Q in {2g,2g+1}, nch=g+1
    int rr = r - g * (g + 1);
    const int Q = 2 * g + rr / (g + 1);
    const int cx = rr % (g + 1);
    const int kstart = cx * CHUNK;
    const int kend = min(kstart + CHUNK, Q * 128 + 128);
    const int ntiles = (kend - kstart) >> 6;   // 1..4 whole tiles
    const int nch_active = Q / 2 + 1;
    const int r0 = Q * 128 + wave * 32;        // this wave's first row

    const unsigned short* qb_p = q + (size_t)b_ * SS * HD;
    const unsigned short* kb_p = k + (size_t)b_ * SS * HD;
    const unsigned short* vb = vT + (size_t)b_ * HD * SS;
    const int* mb = mask + b_ * SS;

    bf16x8 aq[2][2];
#pragma unroll
    for (int rt = 0; rt < 2; ++rt) {
        const unsigned short* qrow = qb_p + (size_t)(r0 + rt * 16 + c) * HD + quad * 8;
        aq[rt][0] = *(const bf16x8*)(qrow);
        aq[rt][1] = *(const bf16x8*)(qrow + 32);
    }

    f32x4 o[2][4];
    float l_i[2][4];
#pragma unroll
    for (int rt = 0; rt < 2; ++rt)
        for (int tt = 0; tt < 4; ++tt) {
            o[rt][tt] = (f32x4){0.f, 0.f, 0.f, 0.f};
            l_i[rt][tt] = 0.f;
        }

    // T14 split staging: global->reg (issue early), reg->LDS (write late).
    bf16x8 sk[2], sv[2];
    auto stage_load = [&](int k0) {
        const unsigned short* ksrc = kb_p + (size_t)k0 * HD;
#pragma unroll
        for (int rnd = 0; rnd < 2; ++rnd) {
            int e = (rnd * 256 + tid) * 8;
            sk[rnd] = *(const bf16x8*)(ksrc + e);
            int t8 = rnd * 256 + tid;
            int vr = t8 >> 3, vc = (t8 & 7) * 8;
            sv[rnd] = *(const bf16x8*)(vb + (size_t)vr * SS + k0 + vc);
        }
    };
    auto stage_write = [&](int buf) {
        unsigned short* kd = &Ks[buf][0];
        unsigned short* vd = &Vs[buf][0];
#pragma unroll
        for (int rnd = 0; rnd < 2; ++rnd) {
            int e = (rnd * 256 + tid) * 8;
            int krow = e >> 6, kcol = e & 63;
            *(bf16x8*)(kd + krow * TST + kcol) = sk[rnd];
            int t8 = rnd * 256 + tid;
            int vr = t8 >> 3, vc = (t8 & 7) * 8;
            *(bf16x8*)(vd + vr * TST + vc) = sv[rnd];
        }
    };

    stage_load(kstart);
    stage_write(0);
    for (int kt = 0; kt < ntiles; ++kt) {
        __syncthreads();
        const int k0 = kstart + kt * KT;
        const bool pre = (kt + 1 < ntiles);
        if (pre) stage_load(k0 + KT);        // issue next tile's globals NOW
        const unsigned short* ks = &Ks[kt & 1][0];
        const unsigned short* vs = &Vs[kt & 1][0];

        // per-tile mask (rt-independent), hoisted
        bool mk4[4];
#pragma unroll
        for (int kg = 0; kg < 4; ++kg) mk4[kg] = (mb[k0 + kg * 16 + c] != 0);

        bf16x8 kf[4][2];
#pragma unroll
        for (int kg = 0; kg < 4; ++kg) {
            kf[kg][0] = *(const bf16x8*)(ks + (kg * 16 + c) * TST + quad * 8);
            kf[kg][1] = *(const bf16x8*)(ks + (kg * 16 + c) * TST + 32 + quad * 8);
        }

        bf16x8 pa[2][2];
#pragma unroll
        for (int rt = 0; rt < 2; ++rt) {
            const int rbase = r0 + rt * 16;
            const bool fullc = (k0 + KT <= rbase);
            f32x4 accs4[4];
            __builtin_amdgcn_s_setprio(1);
#pragma unroll
            for (int kg = 0; kg < 4; ++kg) {
                f32x4 a = (f32x4){0.f, 0.f, 0.f, 0.f};
                a = __builtin_amdgcn_mfma_f32_16x16x32_bf16(aq[rt][0], kf[kg][0], a, 0, 0, 0);
                a = __builtin_amdgcn_mfma_f32_16x16x32_bf16(aq[rt][1], kf[kg][1], a, 0, 0, 0);
                accs4[kg] = a;
            }
            __builtin_amdgcn_s_setprio(0);
            unsigned short* pbuf = &Ps[wave][0];
#pragma unroll
            for (int kg = 0; kg < 4; ++kg) {
                int key = k0 + kg * 16 + c;
                bool mk = mk4[kg];
#pragma unroll
                for (int rr2 = 0; rr2 < 4; ++rr2) {
                    int row = rbase + quad * 4 + rr2;
                    bool keep = mk && (fullc || key <= row);
                    float e = __expf(fminf(accs4[kg][rr2], 80.f));  // scale folded into q
                    float pe = keep ? e : 0.f;
                    l_i[rt][rr2] += pe;
                    pbuf[(quad * 4 + rr2) * PST + kg * 16 + c] = f2bf_trunc(pe);
                }
            }
            pa[rt][0] = *(const bf16x8*)(pbuf + c * PST + quad * 8);
            pa[rt][1] = *(const bf16x8*)(pbuf + c * PST + 32 + quad * 8);
        }

        // PV: V fragments read once, used for both row-tiles
#pragma unroll
        for (int tt = 0; tt < 4; ++tt) {
            bf16x8 bv0 = *(const bf16x8*)(vs + (tt * 16 + c) * TST + quad * 8);
            bf16x8 bv1 = *(const bf16x8*)(vs + (tt * 16 + c) * TST + 32 + quad * 8);
            __builtin_amdgcn_s_setprio(1);
#pragma unroll
            for (int rt = 0; rt < 2; ++rt) {
                o[rt][tt] = __builtin_amdgcn_mfma_f32_16x16x32_bf16(pa[rt][0], bv0, o[rt][tt], 0, 0, 0);
                o[rt][tt] = __builtin_amdgcn_mfma_f32_16x16x32_bf16(pa[rt][1], bv1, o[rt][tt], 0, 0, 0);
            }
            __builtin_amdgcn_s_setprio(0);
        }

        if (pre) stage_write((kt + 1) & 1);  // latency hidden under compute above
    }

#pragma unroll
    for (int rt = 0; rt < 2; ++rt)
        for (int rr2 = 0; rr2 < 4; ++rr2) {
            float s = l_i[rt][rr2];
            s += __shfl_xor(s, 1);
            s += __shfl_xor(s, 2);
            s += __shfl_xor(s, 4);
            s += __shfl_xor(s, 8);
            l_i[rt][rr2] = s;
        }

    if (nch_active == 1) {
        // rows < 256: sole chunk, final output directly
#pragma unroll
        for (int rt = 0; rt < 2; ++rt)
            for (int rr2 = 0; rr2 < 4; ++rr2) {
                int row = r0 + rt * 16 + quad * 4 + rr2;
                float l = l_i[rt][rr2];
                float inv = (l > 0.f) ? 1.f / l : 0.f;
                for (int tt = 0; tt < 4; ++tt)
                    out[((size_t)b_ * SS + row) * HD + tt * 16 + c] = o[rt][tt][rr2] * inv;
            }
        return;
    }

#pragma unroll
    for (int rt = 0; rt < 2; ++rt)
        for (int rr2 = 0; rr2 < 4; ++rr2) {
            int row_abs = r0 + rt * 16 + quad * 4 + rr2;
            int qb_i = row_abs >> 6, rl = row_abs & 63;
            size_t base = (size_t)(b_ * 32 + qb_i) * NCH + cx;
            float l = l_i[rt][rr2];
            float inv = (l > 0.f) ? 1.f / l : 0.f;
            for (int tt = 0; tt < 4; ++tt)
                po[base * 4096 + (size_t)rl * 64 + tt * 16 + c] = f2bf(o[rt][tt][rr2] * inv);
            if (c == 0) pl[base * 64 + rl] = l;
        }
}

// Combine rows >= 256 only: out = sum_c l_c * o_c / sum_c l_c.
// R12: 4 outputs per thread (ushort4 po loads, float4 out stores).
__global__ __launch_bounds__(256) void combine_kernel(
    const unsigned short* __restrict__ po,
    const float* __restrict__ pl,
    float* __restrict__ out) {
    int t = blockIdx.x * 256 + threadIdx.x;
    if (t >= BB * (SS - 256) * (HD / 4)) return;
    int d4 = (t & 15) * 4;
    int rg = t >> 4;
    int b_ = rg / (SS - 256);
    int row = 256 + rg % (SS - 256);
    int qb = row >> 6, rl = row & 63;
    int nch = row / CHUNK + 1;
    size_t base = (size_t)(b_ * 32 + qb) * NCH;
    float L = 0.f;
    float acc0 = 0.f, acc1 = 0.f, acc2 = 0.f, acc3 = 0.f;
    for (int cc = 0; cc < nch; ++cc) {
        float l = pl[(base + cc) * 64 + rl];
        L += l;
        ushort4 pk = *(const ushort4*)(po + (base + cc) * 4096 + (size_t)rl * 64 + d4);
        acc0 += l * bf2f(pk.x);
        acc1 += l * bf2f(pk.y);
        acc2 += l * bf2f(pk.z);
        acc3 += l * bf2f(pk.w);
    }
    float inv = (L > 0.f) ? 1.f / L : 0.f;
    float4 o4;
    o4.x = acc0 * inv; o4.y = acc1 * inv; o4.z = acc2 * inv; o4.w = acc3 * inv;
    *(float4*)(out + ((size_t)b_ * SS + row) * HD + d4) = o4;
}

extern "C" void kernel_launch(void* const* d_in, const int* in_sizes, int n_in,
                              void* d_out, int out_size, void* d_ws, size_t ws_size,
                              hipStream_t stream) {
    const float* x = (const float*)d_in[0];
    const float* Wq = (const float*)d_in[1];
    const float* Wk = (const float*)d_in[2];
    const float* Wv = (const float*)d_in[3];
    const int* mask = (const int*)d_in[4];
    float* out = (float*)d_out;

    // ws: Wt[98304] | q,k,vT[3x1048576] bf16 | po bf16 | pl fp32
    unsigned short* ws = (unsigned short*)d_ws;
    unsigned short* Wt = ws;
    unsigned short* q = Wt + 3 * EE * HD;
    unsigned short* kk = q + (size_t)BB * SS * HD;
    unsigned short* vT = kk + (size_t)BB * SS * HD;
    unsigned short* po = vT + (size_t)BB * SS * HD;
    float* pl = (float*)(po + (size_t)BB * 32 * NCH * 4096);

    pack_w_kernel<<<dim3((3 * EE * HD + 255) / 256), dim3(256), 0, stream>>>(Wq, Wk, Wv, Wt);
    qkv_kernel<<<dim3(BB * SS / 32), dim3(256), 0, stream>>>(x, Wt, q, kk, vT);
    attn_kernel<<<dim3(NITEMS), dim3(256), 0, stream>>>(q, kk, vT, mask, po, pl, out);
    combine_kernel<<<dim3((BB * (SS - 256) * (HD / 4) + 255) / 256), dim3(256), 0, stream>>>(po, pl, out);
}